// Round 6
// baseline (211.356 us; speedup 1.0000x reference)
//
#include <hip/hip_runtime.h>
#include <hip/hip_bf16.h>

// ---------------- types ----------------
typedef __bf16 bf16x8 __attribute__((ext_vector_type(8)));
typedef __bf16 bf16x4 __attribute__((ext_vector_type(4)));
typedef float  f32x4  __attribute__((ext_vector_type(4)));
typedef float  f32x4u __attribute__((ext_vector_type(4), aligned(4)));

// ---------------- problem constants ----------------
#define BATCH 128
#define NSOL  1027
#define IND   257
#define EMB   256
#define OUT_SRC  0ULL
#define OUT_CAND 32768ULL
#define OUT_DST  33587200ULL
#define OUT_DEP  33619968ULL

// workspace layout (bytes)
// W_eff bf16 MFMA-A-frag order, ALL 4 segs: [seg][kk(8)][cg(16)][lane(64)][j(8)]
#define WFRAG_OFF 0
#define BEFF_OFF  524288     // b_eff fp32 [4][256]
#define W256_OFF  528384     // W_eff[:,k=256] fp32 [4][256]

// LDS tile buffer: 32 rows x 264 bf16 (528 B stride; 528 mod 256 == 16 ->
// conflict-free ds_read_b128 A-frag reads) + 32 f32 (k=256 col)
#define XST_B      528
#define X256_OFF_B 16896
#define BUF_B      17024

// ---------------- prep: build effective weights ----------------
__global__ __launch_bounds__(256) void swne_prep(
    const float* __restrict__ Wsrc, const float* __restrict__ bsrc,
    const float* __restrict__ Wdst, const float* __restrict__ bdst,
    const float* __restrict__ Wdep, const float* __restrict__ bdep,
    const float* __restrict__ Wcand, const float* __restrict__ bcand,
    const float* __restrict__ Wreg, const float* __restrict__ breg,
    const float* __restrict__ Wrand, const float* __restrict__ iw,
    char* __restrict__ ws)
{
    const float a  = 1.0f / (1.0f + expf(-iw[0]));
    const float ca = 1.0f - a;
    const float sa = 0.1f * a;

    const float* Ws[4] = {Wsrc, Wcand, Wdst, Wdep};
    const float* Bs[4] = {bsrc, bcand, bdst, bdep};

    const int gid = blockIdx.x * 256 + threadIdx.x;
    const int gsz = gridDim.x * 256;

    float* beff = (float*)(ws + BEFF_OFF);
    float* w256 = (float*)(ws + W256_OFF);
    for (int i = gid; i < 4 * EMB; i += gsz) {
        int seg = i >> 8, e = i & 255;
        beff[i] = ca * Bs[seg][e] + a * breg[e];
        int si = e * IND + 256;
        w256[i] = ca * Ws[seg][si] + a * Wreg[si] + sa * Wrand[si];
    }

    // W_eff bf16 MFMA-A-frag order for all 4 segs, k = 0..255
    __bf16* wfr = (__bf16*)(ws + WFRAG_OFF);
    for (int i = gid; i < 4 * 65536; i += gsz) {
        int seg  = i >> 16;
        int rem  = i & 65535;
        int kk   = rem >> 13;
        int rem2 = rem & 8191;
        int cg   = rem2 >> 9;
        int rem3 = rem2 & 511;
        int l    = rem3 >> 3;
        int j    = rem3 & 7;
        int e = cg * 16 + (l & 15);
        int k = kk * 32 + (l >> 4) * 8 + j;
        int si = e * IND + k;
        wfr[i] = (__bf16)(ca * Ws[seg][si] + a * Wreg[si] + sa * Wrand[si]);
    }
}

// raw barrier: drain LDS ops only — in-flight global loads/stores unaffected
#define BARRIER() { asm volatile("s_waitcnt lgkmcnt(0)" ::: "memory"); \
  __builtin_amdgcn_s_barrier(); asm volatile("" ::: "memory"); }

// issue tile loads into regs (per lane: 8 rows x f32x4; tid<32 also k=256 col)
#define ISSUE(xn) { \
  _Pragma("unroll") for (int rr = 0; rr < 8; ++rr) \
    pf[rr] = *((const f32x4u*)((xn) + (size_t)(wave * 8 + rr) * xstr) + lane); \
  if (tid < 32) pf256 = (xn)[(size_t)tid * xstr + 256]; }

// convert + write staged tile into LDS buffer b (consumes pf late: T14)
#define WRITEB(b) { \
  _Pragma("unroll") for (int rr = 0; rr < 8; ++rr) { \
    const int r_ = wave * 8 + rr; \
    bf16x4 h_; \
    h_[0] = (__bf16)pf[rr][0]; h_[1] = (__bf16)pf[rr][1]; \
    h_[2] = (__bf16)pf[rr][2]; h_[3] = (__bf16)pf[rr][3]; \
    *(bf16x4*)(smem + (b) * BUF_B + r_ * XST_B + lane * 8) = h_; } \
  if (tid < 32) *(float*)(smem + (b) * BUF_B + X256_OFF_B + tid * 4) = pf256; }

// ---------------- main: 12 edge blocks + 1024 cand 4-tile blocks ----------------
__global__ __launch_bounds__(256, 3) void swne_main(const float* __restrict__ sol,
                                                    const char* __restrict__ ws,
                                                    float* __restrict__ out)
{
    __shared__ __align__(16) char smem[2 * BUF_B];   // 34 KiB double buffer
    const int tid = threadIdx.x, bid = blockIdx.x;
    const int lane = tid & 63, wave = tid >> 6;
    const int rl = lane & 15, grp = lane >> 4;

    const float* xbase; size_t xstr; float* obase; int seg, ntiles;
    size_t tstep_x, tstep_o;
    if (bid < 12) {
        const int s3 = bid >> 2;                     // 0:src 1:dst 2:dep
        seg = (s3 == 0) ? 0 : (s3 == 1 ? 2 : 3);
        const int nrow = (s3 == 0) ? 0 : (s3 == 1 ? 1025 : 1026);
        const size_t outb = (s3 == 0) ? OUT_SRC : (s3 == 1 ? OUT_DST : OUT_DEP);
        const int b0 = (bid & 3) * 32;               // 32 batches = tile "rows"
        xbase = sol + ((size_t)b0 * NSOL + nrow) * IND;
        xstr  = (size_t)NSOL * IND;
        obase = out + outb + (size_t)b0 * 256;
        ntiles = 1; tstep_x = 0; tstep_o = 0;
    } else {
        const int c = bid - 12;                      // 0..1023
        seg = 1;
        const int bb = c >> 3, tg = c & 7;           // 8 blocks x 128 rows per batch
        xbase = sol + ((size_t)bb * NSOL + 1 + tg * 128) * IND;
        xstr  = IND;
        obase = out + OUT_CAND + ((size_t)bb * 1024 + tg * 128) * 256;
        ntiles = 4;
        tstep_x = (size_t)32 * IND;
        tstep_o = (size_t)32 * 256;
    }

    const bf16x8* wfs = (const bf16x8*)(ws + WFRAG_OFF) + (size_t)seg * 8192;
    const float* bc = (const float*)(ws + BEFF_OFF) + seg * 256;
    const float* wc = (const float*)(ws + W256_OFF) + seg * 256;

    f32x4 pf[8]; float pf256 = 0.f;

    // prologue: stage tile 0 into buffer 0
    ISSUE(xbase);
    WRITEB(0);
    BARRIER();

    for (int i = 0; i < ntiles; ++i) {
        const bool more = (i + 1 < ntiles);
        if (more) { ISSUE(xbase + (size_t)(i + 1) * tstep_x); }  // loads fly over compute

        // ---- compute tile i from buf (i&1): ds_read_b128 + streamed W + MFMA ----
        const char* xb = smem + (i & 1) * BUF_B;
        f32x4 acc[2][4];
        #pragma unroll
        for (int rt = 0; rt < 2; ++rt)
            #pragma unroll
            for (int n = 0; n < 4; ++n) {
                f32x4 z = {0.f, 0.f, 0.f, 0.f};
                acc[rt][n] = z;
            }
        #pragma unroll
        for (int kk = 0; kk < 8; ++kk) {
            bf16x8 a0 = *(const bf16x8*)(xb + rl * XST_B + kk * 64 + grp * 16);
            bf16x8 a1 = *(const bf16x8*)(xb + (16 + rl) * XST_B + kk * 64 + grp * 16);
            #pragma unroll
            for (int n = 0; n < 4; ++n) {
                bf16x8 wv = wfs[(size_t)((kk * 16 + wave * 4 + n) * 64 + lane)];
                acc[0][n] = __builtin_amdgcn_mfma_f32_16x16x32_bf16(wv, a0, acc[0][n], 0, 0, 0);
                acc[1][n] = __builtin_amdgcn_mfma_f32_16x16x32_bf16(wv, a1, acc[1][n], 0, 0, 0);
            }
        }

        // ---- epilogue: bias + k=256 rank-1 term, f32x4 stores ----
        float* ob = obase + (size_t)i * tstep_o;
        #pragma unroll
        for (int rt = 0; rt < 2; ++rt) {
            const float xl = *(const float*)(xb + X256_OFF_B + (rt * 16 + rl) * 4);
            float* op = ob + (size_t)(rt * 16 + rl) * 256 + wave * 64 + grp * 4;
            #pragma unroll
            for (int n = 0; n < 4; ++n) {
                const int e0 = wave * 64 + n * 16 + grp * 4;
                f32x4 b4 = *(const f32x4*)(bc + e0);
                f32x4 w4 = *(const f32x4*)(wc + e0);
                f32x4 r = acc[rt][n] + xl * w4 + b4;
                *(f32x4*)(op + n * 16) = r;
            }
        }

        if (more) { WRITEB((i + 1) & 1); BARRIER(); }  // write-late; stores drain lazily
    }
}

extern "C" void kernel_launch(void* const* d_in, const int* in_sizes, int n_in,
                              void* d_out, int out_size, void* d_ws, size_t ws_size,
                              hipStream_t stream) {
    const float* sol   = (const float*)d_in[0];
    const float* Wsrc  = (const float*)d_in[1];
    const float* bsrc  = (const float*)d_in[2];
    const float* Wdst  = (const float*)d_in[3];
    const float* bdst  = (const float*)d_in[4];
    const float* Wdep  = (const float*)d_in[5];
    const float* bdep  = (const float*)d_in[6];
    const float* Wcand = (const float*)d_in[7];
    const float* bcand = (const float*)d_in[8];
    const float* Wreg  = (const float*)d_in[9];
    const float* breg  = (const float*)d_in[10];
    const float* Wrand = (const float*)d_in[11];
    const float* iw    = (const float*)d_in[12];

    swne_prep<<<512, 256, 0, stream>>>(Wsrc, bsrc, Wdst, bdst, Wdep, bdep,
                                       Wcand, bcand, Wreg, breg, Wrand, iw,
                                       (char*)d_ws);
    swne_main<<<1036, 256, 0, stream>>>(sol, (const char*)d_ws, (float*)d_out);
}

// Round 7
// 73.262 us; speedup vs baseline: 2.8849x; 2.8849x over previous
//
#include <hip/hip_runtime.h>
#include <hip/hip_bf16.h>

// ---------------- types ----------------
typedef __bf16 bf16x8 __attribute__((ext_vector_type(8)));
typedef __bf16 bf16x4 __attribute__((ext_vector_type(4)));
typedef float  f32x4  __attribute__((ext_vector_type(4)));
typedef float  f32x4u __attribute__((ext_vector_type(4), aligned(4)));

// ---------------- problem constants ----------------
#define BATCH 128
#define NSOL  1027
#define IND   257
#define EMB   256
#define OUT_SRC  0ULL
#define OUT_CAND 32768ULL
#define OUT_DST  33587200ULL
#define OUT_DEP  33619968ULL

// workspace layout (bytes)
// W_eff bf16 MFMA-A-frag order, ALL 4 segs: [seg][kk(8)][cg(16)][lane(64)][j(8)]
#define WFRAG_OFF 0
#define BEFF_OFF  524288     // b_eff fp32 [4][256]
#define W256_OFF  528384     // W_eff[:,k=256] fp32 [4][256]

// LDS tile buffer: 32 rows x 264 bf16 (528 B stride; 528 mod 256 == 16 ->
// conflict-free ds_read_b128 A-frag reads) + 32 f32 (k=256 col)
#define XST_B      528
#define X256_OFF_B 16896
#define BUF_B      17024

// ---------------- prep: build effective weights ----------------
__global__ __launch_bounds__(256) void swne_prep(
    const float* __restrict__ Wsrc, const float* __restrict__ bsrc,
    const float* __restrict__ Wdst, const float* __restrict__ bdst,
    const float* __restrict__ Wdep, const float* __restrict__ bdep,
    const float* __restrict__ Wcand, const float* __restrict__ bcand,
    const float* __restrict__ Wreg, const float* __restrict__ breg,
    const float* __restrict__ Wrand, const float* __restrict__ iw,
    char* __restrict__ ws)
{
    const float a  = 1.0f / (1.0f + expf(-iw[0]));
    const float ca = 1.0f - a;
    const float sa = 0.1f * a;

    const float* Ws[4] = {Wsrc, Wcand, Wdst, Wdep};
    const float* Bs[4] = {bsrc, bcand, bdst, bdep};

    const int gid = blockIdx.x * 256 + threadIdx.x;
    const int gsz = gridDim.x * 256;

    float* beff = (float*)(ws + BEFF_OFF);
    float* w256 = (float*)(ws + W256_OFF);
    for (int i = gid; i < 4 * EMB; i += gsz) {
        int seg = i >> 8, e = i & 255;
        beff[i] = ca * Bs[seg][e] + a * breg[e];
        int si = e * IND + 256;
        w256[i] = ca * Ws[seg][si] + a * Wreg[si] + sa * Wrand[si];
    }

    // W_eff bf16 MFMA-A-frag order for all 4 segs, k = 0..255
    __bf16* wfr = (__bf16*)(ws + WFRAG_OFF);
    for (int i = gid; i < 4 * 65536; i += gsz) {
        int seg  = i >> 16;
        int rem  = i & 65535;
        int kk   = rem >> 13;
        int rem2 = rem & 8191;
        int cg   = rem2 >> 9;
        int rem3 = rem2 & 511;
        int l    = rem3 >> 3;
        int j    = rem3 & 7;
        int e = cg * 16 + (l & 15);
        int k = kk * 32 + (l >> 4) * 8 + j;
        int si = e * IND + k;
        wfr[i] = (__bf16)(ca * Ws[seg][si] + a * Wreg[si] + sa * Wrand[si]);
    }
}

// ---------------- main: 4096 cand + 12 edge 32-row MFMA tiles, uniform path ----
__global__ __launch_bounds__(256, 8) void swne_main(const float* __restrict__ sol,
                                                    const char* __restrict__ ws,
                                                    float* __restrict__ out)
{
    __shared__ __align__(16) char smem[BUF_B];   // 17 KiB single buffer
    const int tid = threadIdx.x, bid = blockIdx.x;
    const int lane = tid & 63, wave = tid >> 6;
    const int rl = lane & 15, grp = lane >> 4;

    const float* xbase; size_t xstr; float* obase; int seg;
    if (bid < 4096) {
        // candidate tile: 32 cand rows of one batch
        const int bb = bid >> 5, t = bid & 31;
        seg   = 1;
        xbase = sol + ((size_t)bb * NSOL + 1 + t * 32) * IND;
        xstr  = IND;
        obase = out + OUT_CAND + ((size_t)bb * 1024 + t * 32) * 256;
    } else {
        // edge tile: 32 batches of one edge node (M-dim = batch)
        const int e = bid - 4096;                // 0..11
        const int s3 = e >> 2, tt = e & 3;       // 0:src 1:dst 2:dep
        seg = (s3 == 0) ? 0 : (s3 == 1 ? 2 : 3);
        const int nrow = (s3 == 0) ? 0 : (s3 == 1 ? 1025 : 1026);
        const size_t outb = (s3 == 0) ? OUT_SRC : (s3 == 1 ? OUT_DST : OUT_DEP);
        xbase = sol + ((size_t)(tt * 32) * NSOL + nrow) * IND;
        xstr  = (size_t)NSOL * IND;
        obase = out + outb + (size_t)(tt * 32) * 256;
    }

    // ---- stage: 32 rows f32 -> bf16 LDS (stride 528 B); coalesced per-row loads
    #pragma unroll
    for (int rr = 0; rr < 8; ++rr) {
        const int r = wave * 8 + rr;
        f32x4u v = *((const f32x4u*)(xbase + (size_t)r * xstr) + lane);
        bf16x4 h;
        h[0] = (__bf16)v[0]; h[1] = (__bf16)v[1];
        h[2] = (__bf16)v[2]; h[3] = (__bf16)v[3];
        *(bf16x4*)(smem + r * XST_B + lane * 8) = h;
    }
    if (tid < 32)
        *(float*)(smem + X256_OFF_B + tid * 4) = xbase[(size_t)tid * xstr + 256];
    __syncthreads();

    // ---- compute: W streamed from L2, X from LDS (conflict-free b128 reads) ----
    const bf16x8* wfs = (const bf16x8*)(ws + WFRAG_OFF) + (size_t)seg * 8192;
    f32x4 acc[2][4];
    #pragma unroll
    for (int rt = 0; rt < 2; ++rt)
        #pragma unroll
        for (int n = 0; n < 4; ++n) {
            f32x4 z = {0.f, 0.f, 0.f, 0.f};
            acc[rt][n] = z;
        }
    #pragma unroll
    for (int kk = 0; kk < 8; ++kk) {
        bf16x8 a0 = *(const bf16x8*)(smem + rl * XST_B + kk * 64 + grp * 16);
        bf16x8 a1 = *(const bf16x8*)(smem + (16 + rl) * XST_B + kk * 64 + grp * 16);
        #pragma unroll
        for (int n = 0; n < 4; ++n) {
            bf16x8 wv = wfs[(size_t)((kk * 16 + wave * 4 + n) * 64 + lane)];
            acc[0][n] = __builtin_amdgcn_mfma_f32_16x16x32_bf16(wv, a0, acc[0][n], 0, 0, 0);
            acc[1][n] = __builtin_amdgcn_mfma_f32_16x16x32_bf16(wv, a1, acc[1][n], 0, 0, 0);
        }
    }

    // ---- epilogue: bias + k=256 rank-1 term, f32x4 stores ----
    const float* bc = (const float*)(ws + BEFF_OFF) + seg * 256;
    const float* wc = (const float*)(ws + W256_OFF) + seg * 256;
    #pragma unroll
    for (int rt = 0; rt < 2; ++rt) {
        const float xl = *(const float*)(smem + X256_OFF_B + (rt * 16 + rl) * 4);
        float* op = obase + (size_t)(rt * 16 + rl) * 256 + wave * 64 + grp * 4;
        #pragma unroll
        for (int n = 0; n < 4; ++n) {
            const int e0 = wave * 64 + n * 16 + grp * 4;
            f32x4 b4 = *(const f32x4*)(bc + e0);
            f32x4 w4 = *(const f32x4*)(wc + e0);
            f32x4 r = acc[rt][n] + xl * w4 + b4;
            *(f32x4*)(op + n * 16) = r;
        }
    }
}

extern "C" void kernel_launch(void* const* d_in, const int* in_sizes, int n_in,
                              void* d_out, int out_size, void* d_ws, size_t ws_size,
                              hipStream_t stream) {
    const float* sol   = (const float*)d_in[0];
    const float* Wsrc  = (const float*)d_in[1];
    const float* bsrc  = (const float*)d_in[2];
    const float* Wdst  = (const float*)d_in[3];
    const float* bdst  = (const float*)d_in[4];
    const float* Wdep  = (const float*)d_in[5];
    const float* bdep  = (const float*)d_in[6];
    const float* Wcand = (const float*)d_in[7];
    const float* bcand = (const float*)d_in[8];
    const float* Wreg  = (const float*)d_in[9];
    const float* breg  = (const float*)d_in[10];
    const float* Wrand = (const float*)d_in[11];
    const float* iw    = (const float*)d_in[12];

    swne_prep<<<512, 256, 0, stream>>>(Wsrc, bsrc, Wdst, bdst, Wdep, bdep,
                                       Wcand, bcand, Wreg, breg, Wrand, iw,
                                       (char*)d_ws);
    swne_main<<<4108, 256, 0, stream>>>(sol, (const char*)d_ws, (float*)d_out);
}

// Round 8
// 67.162 us; speedup vs baseline: 3.1470x; 1.0908x over previous
//
#include <hip/hip_runtime.h>
#include <hip/hip_bf16.h>

// ---------------- types ----------------
typedef __bf16 bf16x8 __attribute__((ext_vector_type(8)));
typedef __bf16 bf16x4 __attribute__((ext_vector_type(4)));
typedef float  f32x4  __attribute__((ext_vector_type(4)));
typedef float  f32x4u __attribute__((ext_vector_type(4), aligned(4)));

// ---------------- problem constants ----------------
#define BATCH 128
#define NSOL  1027
#define IND   257
#define EMB   256
#define OUT_SRC  0ULL
#define OUT_CAND 32768ULL
#define OUT_DST  33587200ULL
#define OUT_DEP  33619968ULL

// workspace layout (bytes)
// W_eff bf16 MFMA-A-frag order, ALL 4 segs: [seg][kk(8)][cg(16)][lane(64)][j(8)]
#define WFRAG_OFF 0
#define BEFF_OFF  524288     // b_eff fp32 [4][256]
#define W256_OFF  528384     // W_eff[:,k=256] fp32 [4][256]

// LDS tile buffer: 32 rows x 264 bf16 (528 B stride; 528 mod 256 == 16 ->
// ~2-way-max bank pattern for ds_read_b128 / ds_write_b64) + 32 f32 (k=256 col)
#define XST_B      528
#define X256_OFF_B 16896
#define BUF_B      17024     // one tile buffer; ring of 4 = 68096 B LDS

// ---------------- prep: build effective weights ----------------
__global__ __launch_bounds__(256) void swne_prep(
    const float* __restrict__ Wsrc, const float* __restrict__ bsrc,
    const float* __restrict__ Wdst, const float* __restrict__ bdst,
    const float* __restrict__ Wdep, const float* __restrict__ bdep,
    const float* __restrict__ Wcand, const float* __restrict__ bcand,
    const float* __restrict__ Wreg, const float* __restrict__ breg,
    const float* __restrict__ Wrand, const float* __restrict__ iw,
    char* __restrict__ ws)
{
    const float a  = 1.0f / (1.0f + expf(-iw[0]));
    const float ca = 1.0f - a;
    const float sa = 0.1f * a;

    const float* Ws[4] = {Wsrc, Wcand, Wdst, Wdep};
    const float* Bs[4] = {bsrc, bcand, bdst, bdep};

    const int gid = blockIdx.x * 256 + threadIdx.x;
    const int gsz = gridDim.x * 256;

    float* beff = (float*)(ws + BEFF_OFF);
    float* w256 = (float*)(ws + W256_OFF);
    for (int i = gid; i < 4 * EMB; i += gsz) {
        int seg = i >> 8, e = i & 255;
        beff[i] = ca * Bs[seg][e] + a * breg[e];
        int si = e * IND + 256;
        w256[i] = ca * Ws[seg][si] + a * Wreg[si] + sa * Wrand[si];
    }

    // W_eff bf16 MFMA-A-frag order for all 4 segs, k = 0..255
    __bf16* wfr = (__bf16*)(ws + WFRAG_OFF);
    for (int i = gid; i < 4 * 65536; i += gsz) {
        int seg  = i >> 16;
        int rem  = i & 65535;
        int kk   = rem >> 13;
        int rem2 = rem & 8191;
        int cg   = rem2 >> 9;
        int rem3 = rem2 & 511;
        int l    = rem3 >> 3;
        int j    = rem3 & 7;
        int e = cg * 16 + (l & 15);
        int k = kk * 32 + (l >> 4) * 8 + j;
        int si = e * IND + k;
        wfr[i] = (__bf16)(ca * Ws[seg][si] + a * Wreg[si] + sa * Wrand[si]);
    }
}

// raw barrier: drain LDS ops only — in-flight global loads/stores unaffected
#define BARRIER() { asm volatile("s_waitcnt lgkmcnt(0)" ::: "memory"); \
  __builtin_amdgcn_s_barrier(); asm volatile("" ::: "memory"); }

// issue one 32-row tile's loads into regs (512 thr: wave w stages rows 4w..4w+3)
#define ISSUE(xb, xstr, pf, pf256) { \
  _Pragma("unroll") for (int rr = 0; rr < 4; ++rr) \
    pf[rr] = *((const f32x4u*)((xb) + (size_t)(wave * 4 + rr) * (xstr)) + lane); \
  if (tid < 32) pf256 = (xb)[(size_t)tid * (xstr) + 256]; }

// convert + write a staged tile into LDS at byte offset boff
#define WRITEB(boff, pf, pf256) { \
  _Pragma("unroll") for (int rr = 0; rr < 4; ++rr) { \
    const int r_ = wave * 4 + rr; \
    bf16x4 h_; \
    h_[0] = (__bf16)pf[rr][0]; h_[1] = (__bf16)pf[rr][1]; \
    h_[2] = (__bf16)pf[rr][2]; h_[3] = (__bf16)pf[rr][3]; \
    *(bf16x4*)(smem + (boff) + r_ * XST_B + lane * 8) = h_; } \
  if (tid < 32) *(float*)(smem + (boff) + X256_OFF_B + tid * 4) = pf256; }

// compute one tile from LDS (register-resident W; no global loads) + store
#define COMPSTORE(boff, obase, W, B4, W4) { \
  f32x4 acc[2][2]; \
  _Pragma("unroll") for (int rt = 0; rt < 2; ++rt) \
    _Pragma("unroll") for (int n = 0; n < 2; ++n) { f32x4 z_ = {0.f,0.f,0.f,0.f}; acc[rt][n] = z_; } \
  _Pragma("unroll") for (int kk = 0; kk < 8; ++kk) { \
    bf16x8 a0 = *(const bf16x8*)(smem + (boff) + rl * XST_B + kk * 64 + grp * 16); \
    bf16x8 a1 = *(const bf16x8*)(smem + (boff) + (16 + rl) * XST_B + kk * 64 + grp * 16); \
    _Pragma("unroll") for (int n = 0; n < 2; ++n) { \
      acc[0][n] = __builtin_amdgcn_mfma_f32_16x16x32_bf16(W[kk][n], a0, acc[0][n], 0, 0, 0); \
      acc[1][n] = __builtin_amdgcn_mfma_f32_16x16x32_bf16(W[kk][n], a1, acc[1][n], 0, 0, 0); } } \
  _Pragma("unroll") for (int rt = 0; rt < 2; ++rt) { \
    const float xl = *(const float*)(smem + (boff) + X256_OFF_B + (rt * 16 + rl) * 4); \
    float* op_ = (obase) + (size_t)(rt * 16 + rl) * 256 + wave * 32 + grp * 4; \
    _Pragma("unroll") for (int n = 0; n < 2; ++n) { \
      f32x4 r_ = acc[rt][n] + xl * W4[n] + B4[n]; \
      *(f32x4*)(op_ + n * 16) = r_; } } }

__device__ __forceinline__ const float* cand_x(const float* sol, int T) {
    const int bb = T >> 5, t = T & 31;
    return sol + ((size_t)bb * NSOL + 1 + t * 32) * IND;
}
__device__ __forceinline__ float* cand_o(float* out, int T) {
    const int bb = T >> 5, t = T & 31;
    return out + OUT_CAND + ((size_t)bb * 1024 + t * 32) * 256;
}

// ---------------- main: 256 blocks x 16 cand tiles (+12 edge tails) ----------------
__global__ __launch_bounds__(512, 1) void swne_main(const float* __restrict__ sol,
                                                    const char* __restrict__ ws,
                                                    float* __restrict__ out)
{
    __shared__ __align__(16) char smem[4 * BUF_B];   // 68 KiB ring of 4 tile buffers
    const int tid = threadIdx.x, bid = blockIdx.x;
    const int lane = tid & 63, wave = tid >> 6;      // 8 waves, wave owns 32 e-cols
    const int rl = lane & 15, grp = lane >> 4;

    const bf16x8* wfb = (const bf16x8*)(ws + WFRAG_OFF);

    // cand (seg=1) W fragments resident: 16 x bf16x8 = 64 VGPR
    bf16x8 wreg[8][2];
    #pragma unroll
    for (int kk = 0; kk < 8; ++kk)
        #pragma unroll
        for (int n = 0; n < 2; ++n)
            wreg[kk][n] = wfb[(size_t)(((8 + kk) * 16) + (wave * 2 + n)) * 64 + lane];

    const float* bc = (const float*)(ws + BEFF_OFF) + 256;   // seg 1
    const float* wc = (const float*)(ws + W256_OFF) + 256;
    f32x4 b4[2], w4[2];
    #pragma unroll
    for (int n = 0; n < 2; ++n) {
        b4[n] = *(const f32x4*)(bc + wave * 32 + n * 16 + grp * 4);
        w4[n] = *(const f32x4*)(wc + wave * 32 + n * 16 + grp * 4);
    }

    const int T0 = bid * 16;
    f32x4 pfA[4], pfB[4]; float pA256 = 0.f, pB256 = 0.f;

    // prologue: tiles 0,1 -> bufs 0,1; prefetch tiles 2,3 into regs
    ISSUE(cand_x(sol, T0 + 0), IND, pfA, pA256);
    ISSUE(cand_x(sol, T0 + 1), IND, pfB, pB256);
    WRITEB(0 * BUF_B, pfA, pA256);
    WRITEB(1 * BUF_B, pfB, pB256);
    ISSUE(cand_x(sol, T0 + 2), IND, pfA, pA256);
    ISSUE(cand_x(sol, T0 + 3), IND, pfB, pB256);
    BARRIER();

    for (int k = 0; k < 16; k += 2) {
        COMPSTORE((size_t)(k & 3) * BUF_B, cand_o(out, T0 + k), wreg, b4, w4);
        if (k + 2 < 16) {
            WRITEB((size_t)((k + 2) & 3) * BUF_B, pfA, pA256);   // tile k+2 (issued 2 tiles ago)
            if (k + 4 < 16) ISSUE(cand_x(sol, T0 + k + 4), IND, pfA, pA256);
        }
        COMPSTORE((size_t)((k + 1) & 3) * BUF_B, cand_o(out, T0 + k + 1), wreg, b4, w4);
        if (k + 3 < 16) {
            WRITEB((size_t)((k + 3) & 3) * BUF_B, pfB, pB256);
            if (k + 5 < 16) ISSUE(cand_x(sol, T0 + k + 5), IND, pfB, pB256);
        }
        BARRIER();
    }

    // ---- edge tail: blocks 0..11 each do one 32-batch edge tile ----
    if (bid < 12) {
        const int s3 = bid >> 2, tt = bid & 3;       // 0:src 1:dst 2:dep
        const int seg = (s3 == 0) ? 0 : (s3 == 1 ? 2 : 3);
        const int nrow = (s3 == 0) ? 0 : (s3 == 1 ? 1025 : 1026);
        const size_t outb = (s3 == 0) ? OUT_SRC : (s3 == 1 ? OUT_DST : OUT_DEP);
        const float* xe = sol + ((size_t)(tt * 32) * NSOL + nrow) * IND;
        float* oe = out + outb + (size_t)(tt * 32) * 256;
        const size_t xstrE = (size_t)NSOL * IND;

        bf16x8 wregE[8][2];
        #pragma unroll
        for (int kk = 0; kk < 8; ++kk)
            #pragma unroll
            for (int n = 0; n < 2; ++n)
                wregE[kk][n] = wfb[(size_t)(((seg * 8 + kk) * 16) + (wave * 2 + n)) * 64 + lane];
        const float* bcE = (const float*)(ws + BEFF_OFF) + seg * 256;
        const float* wcE = (const float*)(ws + W256_OFF) + seg * 256;
        f32x4 b4E[2], w4E[2];
        #pragma unroll
        for (int n = 0; n < 2; ++n) {
            b4E[n] = *(const f32x4*)(bcE + wave * 32 + n * 16 + grp * 4);
            w4E[n] = *(const f32x4*)(wcE + wave * 32 + n * 16 + grp * 4);
        }

        ISSUE(xe, xstrE, pfA, pA256);
        WRITEB(0, pfA, pA256);
        BARRIER();
        COMPSTORE(0, oe, wregE, b4E, w4E);
    }
}

extern "C" void kernel_launch(void* const* d_in, const int* in_sizes, int n_in,
                              void* d_out, int out_size, void* d_ws, size_t ws_size,
                              hipStream_t stream) {
    const float* sol   = (const float*)d_in[0];
    const float* Wsrc  = (const float*)d_in[1];
    const float* bsrc  = (const float*)d_in[2];
    const float* Wdst  = (const float*)d_in[3];
    const float* bdst  = (const float*)d_in[4];
    const float* Wdep  = (const float*)d_in[5];
    const float* bdep  = (const float*)d_in[6];
    const float* Wcand = (const float*)d_in[7];
    const float* bcand = (const float*)d_in[8];
    const float* Wreg  = (const float*)d_in[9];
    const float* breg  = (const float*)d_in[10];
    const float* Wrand = (const float*)d_in[11];
    const float* iw    = (const float*)d_in[12];

    swne_prep<<<512, 256, 0, stream>>>(Wsrc, bsrc, Wdst, bdst, Wdep, bdep,
                                       Wcand, bcand, Wreg, breg, Wrand, iw,
                                       (char*)d_ws);
    swne_main<<<256, 512, 0, stream>>>(sol, (const char*)d_ws, (float*)d_out);
}

// Round 9
// 65.191 us; speedup vs baseline: 3.2421x; 1.0302x over previous
//
#include <hip/hip_runtime.h>
#include <hip/hip_bf16.h>

// ---------------- types ----------------
typedef __bf16 bf16x8 __attribute__((ext_vector_type(8)));
typedef __bf16 bf16x4 __attribute__((ext_vector_type(4)));
typedef float  f32x4  __attribute__((ext_vector_type(4)));
typedef float  f32x4u __attribute__((ext_vector_type(4), aligned(4)));

// ---------------- problem constants ----------------
#define BATCH 128
#define NSOL  1027
#define IND   257
#define EMB   256
#define OUT_SRC  0ULL
#define OUT_CAND 32768ULL
#define OUT_DST  33587200ULL
#define OUT_DEP  33619968ULL

// workspace layout (bytes)
// W_eff bf16 MFMA-A-frag order, ALL 4 segs: [seg][kk(8)][cg(16)][lane(64)][j(8)]
#define WFRAG_OFF 0
#define BEFF_OFF  524288     // b_eff fp32 [4][256]
#define W256_OFF  528384     // W_eff[:,k=256] fp32 [4][256]

// LDS tile buffer: 32 rows x 264 bf16 (528 B stride; 528 mod 256 == 16 ->
// ~2-way-max bank pattern for ds_read_b128 / ds_write_b64) + 32 f32 (k=256 col)
#define XST_B      528
#define X256_OFF_B 16896
#define BUF_B      17024     // one tile buffer; ring of 4 = 68096 B LDS

// ---------------- prep: build effective weights ----------------
__global__ __launch_bounds__(256) void swne_prep(
    const float* __restrict__ Wsrc, const float* __restrict__ bsrc,
    const float* __restrict__ Wdst, const float* __restrict__ bdst,
    const float* __restrict__ Wdep, const float* __restrict__ bdep,
    const float* __restrict__ Wcand, const float* __restrict__ bcand,
    const float* __restrict__ Wreg, const float* __restrict__ breg,
    const float* __restrict__ Wrand, const float* __restrict__ iw,
    char* __restrict__ ws)
{
    const float a  = 1.0f / (1.0f + expf(-iw[0]));
    const float ca = 1.0f - a;
    const float sa = 0.1f * a;

    const float* Ws[4] = {Wsrc, Wcand, Wdst, Wdep};
    const float* Bs[4] = {bsrc, bcand, bdst, bdep};

    const int gid = blockIdx.x * 256 + threadIdx.x;
    const int gsz = gridDim.x * 256;

    float* beff = (float*)(ws + BEFF_OFF);
    float* w256 = (float*)(ws + W256_OFF);
    for (int i = gid; i < 4 * EMB; i += gsz) {
        int seg = i >> 8, e = i & 255;
        beff[i] = ca * Bs[seg][e] + a * breg[e];
        int si = e * IND + 256;
        w256[i] = ca * Ws[seg][si] + a * Wreg[si] + sa * Wrand[si];
    }

    // W_eff bf16 MFMA-A-frag order for all 4 segs, k = 0..255
    __bf16* wfr = (__bf16*)(ws + WFRAG_OFF);
    for (int i = gid; i < 4 * 65536; i += gsz) {
        int seg  = i >> 16;
        int rem  = i & 65535;
        int kk   = rem >> 13;
        int rem2 = rem & 8191;
        int cg   = rem2 >> 9;
        int rem3 = rem2 & 511;
        int l    = rem3 >> 3;
        int j    = rem3 & 7;
        int e = cg * 16 + (l & 15);
        int k = kk * 32 + (l >> 4) * 8 + j;
        int si = e * IND + k;
        wfr[i] = (__bf16)(ca * Ws[seg][si] + a * Wreg[si] + sa * Wrand[si]);
    }
}

// raw barrier: drain LDS ops only — in-flight global loads/stores unaffected
#define BARRIER() { asm volatile("s_waitcnt lgkmcnt(0)" ::: "memory"); \
  __builtin_amdgcn_s_barrier(); asm volatile("" ::: "memory"); }

// issue one 32-row tile's loads into regs (512 thr: wave w stages rows 4w..4w+3)
#define ISSUE(xb, xstr, pf, pf256) { \
  _Pragma("unroll") for (int rr = 0; rr < 4; ++rr) \
    pf[rr] = *((const f32x4u*)((xb) + (size_t)(wave * 4 + rr) * (xstr)) + lane); \
  if (tid < 32) pf256 = (xb)[(size_t)tid * (xstr) + 256]; }

// convert + write a staged tile into LDS at byte offset boff
#define WRITEB(boff, pf, pf256) { \
  _Pragma("unroll") for (int rr = 0; rr < 4; ++rr) { \
    const int r_ = wave * 4 + rr; \
    bf16x4 h_; \
    h_[0] = (__bf16)pf[rr][0]; h_[1] = (__bf16)pf[rr][1]; \
    h_[2] = (__bf16)pf[rr][2]; h_[3] = (__bf16)pf[rr][3]; \
    *(bf16x4*)(smem + (boff) + r_ * XST_B + lane * 8) = h_; } \
  if (tid < 32) *(float*)(smem + (boff) + X256_OFF_B + tid * 4) = pf256; }

// compute one tile from LDS (register-resident W; no global loads) + store
#define COMPSTORE(boff, obase, W, B4, W4) { \
  f32x4 acc[2][2]; \
  _Pragma("unroll") for (int rt = 0; rt < 2; ++rt) \
    _Pragma("unroll") for (int n = 0; n < 2; ++n) { f32x4 z_ = {0.f,0.f,0.f,0.f}; acc[rt][n] = z_; } \
  _Pragma("unroll") for (int kk = 0; kk < 8; ++kk) { \
    bf16x8 a0 = *(const bf16x8*)(smem + (boff) + rl * XST_B + kk * 64 + grp * 16); \
    bf16x8 a1 = *(const bf16x8*)(smem + (boff) + (16 + rl) * XST_B + kk * 64 + grp * 16); \
    _Pragma("unroll") for (int n = 0; n < 2; ++n) { \
      acc[0][n] = __builtin_amdgcn_mfma_f32_16x16x32_bf16(W[kk][n], a0, acc[0][n], 0, 0, 0); \
      acc[1][n] = __builtin_amdgcn_mfma_f32_16x16x32_bf16(W[kk][n], a1, acc[1][n], 0, 0, 0); } } \
  _Pragma("unroll") for (int rt = 0; rt < 2; ++rt) { \
    const float xl = *(const float*)(smem + (boff) + X256_OFF_B + (rt * 16 + rl) * 4); \
    float* op_ = (obase) + (size_t)(rt * 16 + rl) * 256 + wave * 32 + grp * 4; \
    _Pragma("unroll") for (int n = 0; n < 2; ++n) { \
      f32x4 r_ = acc[rt][n] + xl * W4[n] + B4[n]; \
      *(f32x4*)(op_ + n * 16) = r_; } } }

__device__ __forceinline__ const float* cand_x(const float* sol, int T) {
    const int bb = T >> 5, t = T & 31;
    return sol + ((size_t)bb * NSOL + 1 + t * 32) * IND;
}
__device__ __forceinline__ float* cand_o(float* out, int T) {
    const int bb = T >> 5, t = T & 31;
    return out + OUT_CAND + ((size_t)bb * 1024 + t * 32) * 256;
}

// ---------------- main: 512 blocks x 8 cand tiles (+12 edge tails) ----------------
__global__ __launch_bounds__(512, 2) void swne_main(const float* __restrict__ sol,
                                                    const char* __restrict__ ws,
                                                    float* __restrict__ out)
{
    __shared__ __align__(16) char smem[4 * BUF_B];   // 68 KiB ring of 4 tile buffers
    const int tid = threadIdx.x, bid = blockIdx.x;
    const int lane = tid & 63, wave = tid >> 6;      // 8 waves, wave owns 32 e-cols
    const int rl = lane & 15, grp = lane >> 4;

    const bf16x8* wfb = (const bf16x8*)(ws + WFRAG_OFF);

    // cand (seg=1) W fragments resident: 16 x bf16x8 = 64 VGPR
    bf16x8 wreg[8][2];
    #pragma unroll
    for (int kk = 0; kk < 8; ++kk)
        #pragma unroll
        for (int n = 0; n < 2; ++n)
            wreg[kk][n] = wfb[(size_t)(((8 + kk) * 16) + (wave * 2 + n)) * 64 + lane];

    const float* bc = (const float*)(ws + BEFF_OFF) + 256;   // seg 1
    const float* wc = (const float*)(ws + W256_OFF) + 256;
    f32x4 b4[2], w4[2];
    #pragma unroll
    for (int n = 0; n < 2; ++n) {
        b4[n] = *(const f32x4*)(bc + wave * 32 + n * 16 + grp * 4);
        w4[n] = *(const f32x4*)(wc + wave * 32 + n * 16 + grp * 4);
    }

    const int T0 = bid * 8;
    f32x4 pfA[4], pfB[4]; float pA256 = 0.f, pB256 = 0.f;

    // prologue: tiles 0,1 -> bufs 0,1; prefetch tiles 2,3 into regs
    ISSUE(cand_x(sol, T0 + 0), IND, pfA, pA256);
    ISSUE(cand_x(sol, T0 + 1), IND, pfB, pB256);
    WRITEB(0 * BUF_B, pfA, pA256);
    WRITEB(1 * BUF_B, pfB, pB256);
    ISSUE(cand_x(sol, T0 + 2), IND, pfA, pA256);
    ISSUE(cand_x(sol, T0 + 3), IND, pfB, pB256);
    BARRIER();

    for (int k = 0; k < 8; k += 2) {
        COMPSTORE((size_t)(k & 3) * BUF_B, cand_o(out, T0 + k), wreg, b4, w4);
        if (k + 2 < 8) {
            WRITEB((size_t)((k + 2) & 3) * BUF_B, pfA, pA256);   // tile k+2 (issued 2 tiles ago)
            if (k + 4 < 8) ISSUE(cand_x(sol, T0 + k + 4), IND, pfA, pA256);
        }
        COMPSTORE((size_t)((k + 1) & 3) * BUF_B, cand_o(out, T0 + k + 1), wreg, b4, w4);
        if (k + 3 < 8) {
            WRITEB((size_t)((k + 3) & 3) * BUF_B, pfB, pB256);
            if (k + 5 < 8) ISSUE(cand_x(sol, T0 + k + 5), IND, pfB, pB256);
        }
        BARRIER();
    }

    // ---- edge tail: blocks 0..11 each do one 32-batch edge tile ----
    if (bid < 12) {
        const int s3 = bid >> 2, tt = bid & 3;       // 0:src 1:dst 2:dep
        const int seg = (s3 == 0) ? 0 : (s3 == 1 ? 2 : 3);
        const int nrow = (s3 == 0) ? 0 : (s3 == 1 ? 1025 : 1026);
        const size_t outb = (s3 == 0) ? OUT_SRC : (s3 == 1 ? OUT_DST : OUT_DEP);
        const float* xe = sol + ((size_t)(tt * 32) * NSOL + nrow) * IND;
        float* oe = out + outb + (size_t)(tt * 32) * 256;
        const size_t xstrE = (size_t)NSOL * IND;

        bf16x8 wregE[8][2];
        #pragma unroll
        for (int kk = 0; kk < 8; ++kk)
            #pragma unroll
            for (int n = 0; n < 2; ++n)
                wregE[kk][n] = wfb[(size_t)(((seg * 8 + kk) * 16) + (wave * 2 + n)) * 64 + lane];
        const float* bcE = (const float*)(ws + BEFF_OFF) + seg * 256;
        const float* wcE = (const float*)(ws + W256_OFF) + seg * 256;
        f32x4 b4E[2], w4E[2];
        #pragma unroll
        for (int n = 0; n < 2; ++n) {
            b4E[n] = *(const f32x4*)(bcE + wave * 32 + n * 16 + grp * 4);
            w4E[n] = *(const f32x4*)(wcE + wave * 32 + n * 16 + grp * 4);
        }

        ISSUE(xe, xstrE, pfA, pA256);
        WRITEB(0, pfA, pA256);
        BARRIER();
        COMPSTORE(0, oe, wregE, b4E, w4E);
    }
}

extern "C" void kernel_launch(void* const* d_in, const int* in_sizes, int n_in,
                              void* d_out, int out_size, void* d_ws, size_t ws_size,
                              hipStream_t stream) {
    const float* sol   = (const float*)d_in[0];
    const float* Wsrc  = (const float*)d_in[1];
    const float* bsrc  = (const float*)d_in[2];
    const float* Wdst  = (const float*)d_in[3];
    const float* bdst  = (const float*)d_in[4];
    const float* Wdep  = (const float*)d_in[5];
    const float* bdep  = (const float*)d_in[6];
    const float* Wcand = (const float*)d_in[7];
    const float* bcand = (const float*)d_in[8];
    const float* Wreg  = (const float*)d_in[9];
    const float* breg  = (const float*)d_in[10];
    const float* Wrand = (const float*)d_in[11];
    const float* iw    = (const float*)d_in[12];

    swne_prep<<<512, 256, 0, stream>>>(Wsrc, bsrc, Wdst, bdst, Wdep, bdep,
                                       Wcand, bcand, Wreg, breg, Wrand, iw,
                                       (char*)d_ws);
    swne_main<<<512, 512, 0, stream>>>(sol, (const char*)d_ws, (float*)d_out);
}

// Round 10
// 63.617 us; speedup vs baseline: 3.3223x; 1.0247x over previous
//
#include <hip/hip_runtime.h>
#include <hip/hip_bf16.h>

// ---------------- types ----------------
typedef __bf16 bf16x8 __attribute__((ext_vector_type(8)));
typedef __bf16 bf16x4 __attribute__((ext_vector_type(4)));
typedef float  f32x4  __attribute__((ext_vector_type(4)));
typedef float  f32x4u __attribute__((ext_vector_type(4), aligned(4)));

// ---------------- problem constants ----------------
#define BATCH 128
#define NSOL  1027
#define IND   257
#define EMB   256
#define OUT_SRC  0ULL
#define OUT_CAND 32768ULL
#define OUT_DST  33587200ULL
#define OUT_DEP  33619968ULL

// workspace layout (bytes)
// W_eff bf16 MFMA-A-frag order, ALL 4 segs: [seg][kk(8)][cg(16)][lane(64)][j(8)]
#define WFRAG_OFF 0
#define BEFF_OFF  524288     // b_eff fp32 [4][256]
#define W256_OFF  528384     // W_eff[:,k=256] fp32 [4][256]

// LDS tile buffer: 32 rows x 264 bf16 (528 B stride; 528 mod 256 == 16 ->
// ~2-way-max bank pattern for ds_read_b128 / ds_write_b64) + 32 f32 (k=256 col)
#define XST_B      528
#define X256_OFF_B 16896
#define BUF_B      17024     // one tile buffer; ring of 4 = 68096 B LDS

// ---------------- prep: build effective weights ----------------
__global__ __launch_bounds__(256) void swne_prep(
    const float* __restrict__ Wsrc, const float* __restrict__ bsrc,
    const float* __restrict__ Wdst, const float* __restrict__ bdst,
    const float* __restrict__ Wdep, const float* __restrict__ bdep,
    const float* __restrict__ Wcand, const float* __restrict__ bcand,
    const float* __restrict__ Wreg, const float* __restrict__ breg,
    const float* __restrict__ Wrand, const float* __restrict__ iw,
    char* __restrict__ ws)
{
    const float a  = 1.0f / (1.0f + expf(-iw[0]));
    const float ca = 1.0f - a;
    const float sa = 0.1f * a;

    const float* Ws[4] = {Wsrc, Wcand, Wdst, Wdep};
    const float* Bs[4] = {bsrc, bcand, bdst, bdep};

    const int gid = blockIdx.x * 256 + threadIdx.x;
    const int gsz = gridDim.x * 256;

    float* beff = (float*)(ws + BEFF_OFF);
    float* w256 = (float*)(ws + W256_OFF);
    for (int i = gid; i < 4 * EMB; i += gsz) {
        int seg = i >> 8, e = i & 255;
        beff[i] = ca * Bs[seg][e] + a * breg[e];
        int si = e * IND + 256;
        w256[i] = ca * Ws[seg][si] + a * Wreg[si] + sa * Wrand[si];
    }

    // W_eff bf16 MFMA-A-frag order for all 4 segs, k = 0..255
    __bf16* wfr = (__bf16*)(ws + WFRAG_OFF);
    for (int i = gid; i < 4 * 65536; i += gsz) {
        int seg  = i >> 16;
        int rem  = i & 65535;
        int kk   = rem >> 13;
        int rem2 = rem & 8191;
        int cg   = rem2 >> 9;
        int rem3 = rem2 & 511;
        int l    = rem3 >> 3;
        int j    = rem3 & 7;
        int e = cg * 16 + (l & 15);
        int k = kk * 32 + (l >> 4) * 8 + j;
        int si = e * IND + k;
        wfr[i] = (__bf16)(ca * Ws[seg][si] + a * Wreg[si] + sa * Wrand[si]);
    }
}

// raw barrier: drain LDS ops only — in-flight global loads/stores unaffected
#define BARRIER() { asm volatile("s_waitcnt lgkmcnt(0)" ::: "memory"); \
  __builtin_amdgcn_s_barrier(); asm volatile("" ::: "memory"); }

// issue one 32-row tile's loads into regs (512 thr: wave w stages rows 4w..4w+3)
#define ISSUE(xb, xstr, pf, pf256) { \
  _Pragma("unroll") for (int rr = 0; rr < 4; ++rr) \
    pf[rr] = *((const f32x4u*)((xb) + (size_t)(wave * 4 + rr) * (xstr)) + lane); \
  if (tid < 32) pf256 = (xb)[(size_t)tid * (xstr) + 256]; }

// convert + write a staged tile into LDS at byte offset boff
#define WRITEB(boff, pf, pf256) { \
  _Pragma("unroll") for (int rr = 0; rr < 4; ++rr) { \
    const int r_ = wave * 4 + rr; \
    bf16x4 h_; \
    h_[0] = (__bf16)pf[rr][0]; h_[1] = (__bf16)pf[rr][1]; \
    h_[2] = (__bf16)pf[rr][2]; h_[3] = (__bf16)pf[rr][3]; \
    *(bf16x4*)(smem + (boff) + r_ * XST_B + lane * 8) = h_; } \
  if (tid < 32) *(float*)(smem + (boff) + X256_OFF_B + tid * 4) = pf256; }

// compute one tile from LDS (register-resident W; no global loads) + nt-store
#define COMPSTORE(boff, obase, W, B4, W4) { \
  f32x4 acc[2][2]; \
  _Pragma("unroll") for (int rt = 0; rt < 2; ++rt) \
    _Pragma("unroll") for (int n = 0; n < 2; ++n) { f32x4 z_ = {0.f,0.f,0.f,0.f}; acc[rt][n] = z_; } \
  _Pragma("unroll") for (int kk = 0; kk < 8; ++kk) { \
    bf16x8 a0 = *(const bf16x8*)(smem + (boff) + rl * XST_B + kk * 64 + grp * 16); \
    bf16x8 a1 = *(const bf16x8*)(smem + (boff) + (16 + rl) * XST_B + kk * 64 + grp * 16); \
    _Pragma("unroll") for (int n = 0; n < 2; ++n) { \
      acc[0][n] = __builtin_amdgcn_mfma_f32_16x16x32_bf16(W[kk][n], a0, acc[0][n], 0, 0, 0); \
      acc[1][n] = __builtin_amdgcn_mfma_f32_16x16x32_bf16(W[kk][n], a1, acc[1][n], 0, 0, 0); } } \
  _Pragma("unroll") for (int rt = 0; rt < 2; ++rt) { \
    const float xl = *(const float*)(smem + (boff) + X256_OFF_B + (rt * 16 + rl) * 4); \
    float* op_ = (obase) + (size_t)(rt * 16 + rl) * 256 + wave * 32 + grp * 4; \
    _Pragma("unroll") for (int n = 0; n < 2; ++n) { \
      f32x4 r_ = acc[rt][n] + xl * W4[n] + B4[n]; \
      __builtin_nontemporal_store(r_, (f32x4*)(op_ + n * 16)); } } }

__device__ __forceinline__ const float* cand_x(const float* sol, int T) {
    const int bb = T >> 5, t = T & 31;
    return sol + ((size_t)bb * NSOL + 1 + t * 32) * IND;
}
__device__ __forceinline__ float* cand_o(float* out, int T) {
    const int bb = T >> 5, t = T & 31;
    return out + OUT_CAND + ((size_t)bb * 1024 + t * 32) * 256;
}

// ---------------- main: 512 blocks x 8 cand tiles (+12 edge tails) ----------------
__global__ __launch_bounds__(512, 2) void swne_main(const float* __restrict__ sol,
                                                    const char* __restrict__ ws,
                                                    float* __restrict__ out)
{
    __shared__ __align__(16) char smem[4 * BUF_B];   // 68 KiB ring of 4 tile buffers
    const int tid = threadIdx.x, bid = blockIdx.x;
    const int lane = tid & 63, wave = tid >> 6;      // 8 waves, wave owns 32 e-cols
    const int rl = lane & 15, grp = lane >> 4;

    const bf16x8* wfb = (const bf16x8*)(ws + WFRAG_OFF);

    // cand (seg=1) W fragments resident: 16 x bf16x8 = 64 VGPR
    bf16x8 wreg[8][2];
    #pragma unroll
    for (int kk = 0; kk < 8; ++kk)
        #pragma unroll
        for (int n = 0; n < 2; ++n)
            wreg[kk][n] = wfb[(size_t)(((8 + kk) * 16) + (wave * 2 + n)) * 64 + lane];

    const float* bc = (const float*)(ws + BEFF_OFF) + 256;   // seg 1
    const float* wc = (const float*)(ws + W256_OFF) + 256;
    f32x4 b4[2], w4[2];
    #pragma unroll
    for (int n = 0; n < 2; ++n) {
        b4[n] = *(const f32x4*)(bc + wave * 32 + n * 16 + grp * 4);
        w4[n] = *(const f32x4*)(wc + wave * 32 + n * 16 + grp * 4);
    }

    const int T0 = bid * 8;
    f32x4 pfA[4], pfB[4]; float pA256 = 0.f, pB256 = 0.f;

    // prologue: tiles 0,1 -> bufs 0,1; prefetch tiles 2,3 into regs
    ISSUE(cand_x(sol, T0 + 0), IND, pfA, pA256);
    ISSUE(cand_x(sol, T0 + 1), IND, pfB, pB256);
    WRITEB(0 * BUF_B, pfA, pA256);
    WRITEB(1 * BUF_B, pfB, pB256);
    ISSUE(cand_x(sol, T0 + 2), IND, pfA, pA256);
    ISSUE(cand_x(sol, T0 + 3), IND, pfB, pB256);
    BARRIER();

    for (int k = 0; k < 8; k += 2) {
        COMPSTORE((size_t)(k & 3) * BUF_B, cand_o(out, T0 + k), wreg, b4, w4);
        if (k + 2 < 8) {
            WRITEB((size_t)((k + 2) & 3) * BUF_B, pfA, pA256);   // tile k+2 (issued 2 tiles ago)
            if (k + 4 < 8) ISSUE(cand_x(sol, T0 + k + 4), IND, pfA, pA256);
        }
        COMPSTORE((size_t)((k + 1) & 3) * BUF_B, cand_o(out, T0 + k + 1), wreg, b4, w4);
        if (k + 3 < 8) {
            WRITEB((size_t)((k + 3) & 3) * BUF_B, pfB, pB256);
            if (k + 5 < 8) ISSUE(cand_x(sol, T0 + k + 5), IND, pfB, pB256);
        }
        BARRIER();
    }

    // ---- edge tail: blocks 0..11 each do one 32-batch edge tile ----
    if (bid < 12) {
        const int s3 = bid >> 2, tt = bid & 3;       // 0:src 1:dst 2:dep
        const int seg = (s3 == 0) ? 0 : (s3 == 1 ? 2 : 3);
        const int nrow = (s3 == 0) ? 0 : (s3 == 1 ? 1025 : 1026);
        const size_t outb = (s3 == 0) ? OUT_SRC : (s3 == 1 ? OUT_DST : OUT_DEP);
        const float* xe = sol + ((size_t)(tt * 32) * NSOL + nrow) * IND;
        float* oe = out + outb + (size_t)(tt * 32) * 256;
        const size_t xstrE = (size_t)NSOL * IND;

        bf16x8 wregE[8][2];
        #pragma unroll
        for (int kk = 0; kk < 8; ++kk)
            #pragma unroll
            for (int n = 0; n < 2; ++n)
                wregE[kk][n] = wfb[(size_t)(((seg * 8 + kk) * 16) + (wave * 2 + n)) * 64 + lane];
        const float* bcE = (const float*)(ws + BEFF_OFF) + seg * 256;
        const float* wcE = (const float*)(ws + W256_OFF) + seg * 256;
        f32x4 b4E[2], w4E[2];
        #pragma unroll
        for (int n = 0; n < 2; ++n) {
            b4E[n] = *(const f32x4*)(bcE + wave * 32 + n * 16 + grp * 4);
            w4E[n] = *(const f32x4*)(wcE + wave * 32 + n * 16 + grp * 4);
        }

        ISSUE(xe, xstrE, pfA, pA256);
        WRITEB(0, pfA, pA256);
        BARRIER();
        COMPSTORE(0, oe, wregE, b4E, w4E);
    }
}

extern "C" void kernel_launch(void* const* d_in, const int* in_sizes, int n_in,
                              void* d_out, int out_size, void* d_ws, size_t ws_size,
                              hipStream_t stream) {
    const float* sol   = (const float*)d_in[0];
    const float* Wsrc  = (const float*)d_in[1];
    const float* bsrc  = (const float*)d_in[2];
    const float* Wdst  = (const float*)d_in[3];
    const float* bdst  = (const float*)d_in[4];
    const float* Wdep  = (const float*)d_in[5];
    const float* bdep  = (const float*)d_in[6];
    const float* Wcand = (const float*)d_in[7];
    const float* bcand = (const float*)d_in[8];
    const float* Wreg  = (const float*)d_in[9];
    const float* breg  = (const float*)d_in[10];
    const float* Wrand = (const float*)d_in[11];
    const float* iw    = (const float*)d_in[12];

    swne_prep<<<512, 256, 0, stream>>>(Wsrc, bsrc, Wdst, bdst, Wdep, bdep,
                                       Wcand, bcand, Wreg, breg, Wrand, iw,
                                       (char*)d_ws);
    swne_main<<<512, 512, 0, stream>>>(sol, (const char*)d_ws, (float*)d_out);
}